// Round 1
// baseline (1600.312 us; speedup 1.0000x reference)
//
#include <hip/hip_runtime.h>
#include <hip/hip_bf16.h>

// Problem constants (match reference)
#define NN 100000
#define NE 500000
#define DD 128
#define HID 128
#define RELS 4
#define NCLS 16
#define SCAN_B 1024
#define NCHUNK ((NN + SCAN_B - 1) / SCAN_B)   // 98

// ---------------- CSR build ----------------

__global__ void hist_kernel(const int* __restrict__ e0, const int* __restrict__ e1,
                            const int* __restrict__ e2, const int* __restrict__ e3,
                            int* __restrict__ counts) {
    int i = blockIdx.x * 256 + threadIdx.x;
    int rel = blockIdx.y;
    if (i >= NE) return;
    const int* ep = (rel == 0) ? e0 : (rel == 1) ? e1 : (rel == 2) ? e2 : e3;
    int d = ep[NE + i];              // dst row
    atomicAdd(&counts[rel * NN + d], 1);
}

__global__ void scanA_kernel(const int* __restrict__ counts, int* __restrict__ bsums) {
    int rel = blockIdx.y, chunk = blockIdx.x;
    int i = chunk * SCAN_B + threadIdx.x;
    __shared__ int s[SCAN_B];
    int v = (i < NN) ? counts[rel * NN + i] : 0;
    s[threadIdx.x] = v;
    __syncthreads();
    for (int off = SCAN_B / 2; off > 0; off >>= 1) {
        if (threadIdx.x < off) s[threadIdx.x] += s[threadIdx.x + off];
        __syncthreads();
    }
    if (threadIdx.x == 0) bsums[rel * 128 + chunk] = s[0];
}

__global__ void scanB_kernel(int* __restrict__ bsums, int* __restrict__ rowptr) {
    int r = threadIdx.x;
    if (r < RELS) {
        int acc = 0;
        for (int c = 0; c < NCHUNK; ++c) {
            int v = bsums[r * 128 + c];
            bsums[r * 128 + c] = acc;
            acc += v;
        }
        rowptr[r * (NN + 1) + NN] = acc;   // == NE
    }
}

__global__ void scanC_kernel(const int* __restrict__ counts, const int* __restrict__ bsums,
                             int* __restrict__ rowptr) {
    int rel = blockIdx.y, chunk = blockIdx.x;
    int i = chunk * SCAN_B + threadIdx.x;
    __shared__ int s[SCAN_B];
    int v = (i < NN) ? counts[rel * NN + i] : 0;
    s[threadIdx.x] = v;
    __syncthreads();
    // Hillis-Steele inclusive scan
    for (int off = 1; off < SCAN_B; off <<= 1) {
        int add = (threadIdx.x >= (unsigned)off) ? s[threadIdx.x - off] : 0;
        __syncthreads();
        s[threadIdx.x] += add;
        __syncthreads();
    }
    if (i < NN)
        rowptr[rel * (NN + 1) + i] = bsums[rel * 128 + chunk] + s[threadIdx.x] - v;
}

__global__ void fill_kernel(const int* __restrict__ e0, const int* __restrict__ e1,
                            const int* __restrict__ e2, const int* __restrict__ e3,
                            const int* __restrict__ rowptr, int* __restrict__ cursor,
                            int* __restrict__ col) {
    int i = blockIdx.x * 256 + threadIdx.x;
    int rel = blockIdx.y;
    if (i >= NE) return;
    const int* ep = (rel == 0) ? e0 : (rel == 1) ? e1 : (rel == 2) ? e2 : e3;
    int src = ep[i];
    int dst = ep[NE + i];
    int p = atomicAdd(&cursor[rel * NN + dst], 1);
    col[rel * NE + rowptr[rel * (NN + 1) + dst] + p] = src;
}

// ---------------- weight pre-reduction ----------------
// Wsum[l] = sum_r W_root[l,r]  (since sum_r x@Wr_r = x@(sum_r Wr_r))
// bsum[l] = sum_r b_nbr[l,r]

__global__ void wsum_kernel(const float* __restrict__ Wr, const float* __restrict__ bn,
                            float* __restrict__ Ws, float* __restrict__ bs) {
    int i = blockIdx.x * 256 + threadIdx.x;
    if (i < 2 * 16384) {
        int l = i >> 14, off = i & 16383;
        float a = 0.f;
        for (int r = 0; r < RELS; ++r) a += Wr[(l * RELS + r) * 16384 + off];
        Ws[i] = a;
    }
    if (i < 2 * 128) {
        int l = i >> 7, off = i & 127;
        float a = 0.f;
        for (int r = 0; r < RELS; ++r) a += bn[(l * RELS + r) * 128 + off];
        bs[i] = a;
    }
}

// ---------------- mean aggregation via CSR ----------------
// 128 threads per node; 2 nodes per 256-thread block.

__global__ void aggregate_kernel(const int* __restrict__ rowptr, const int* __restrict__ col,
                                 const float* __restrict__ x, float* __restrict__ agg) {
    int node = blockIdx.x * 2 + (threadIdx.x >> 7);
    int d = threadIdx.x & 127;
    int s = rowptr[node], e = rowptr[node + 1];
    float acc = 0.f;
    for (int k = s; k < e; ++k) {
        int src = col[k];                 // same addr across 128 lanes -> broadcast
        acc += x[src * DD + d];           // coalesced row read
    }
    float scale = (e > s) ? 1.0f / (float)(e - s) : 0.0f;
    agg[node * DD + d] = acc * scale;
}

// ---------------- init hidden with bias ----------------

__global__ void init_bias_kernel(float* __restrict__ h, const float* __restrict__ bsum) {
    int i = blockIdx.x * 256 + threadIdx.x;
    if (i < NN * HID) h[i] = bsum[i & 127];
}

// ---------------- fp32 GEMM-accumulate: C[M,128] += A[M,128] @ B[128,128] ----------------
// BM=64, BN=128, BK=16, 256 threads, per-thread 4x8 tile.

template <bool RELU>
__global__ void gemm_acc_kernel(const float* __restrict__ A, const float* __restrict__ B,
                                float* __restrict__ C, int M) {
    __shared__ float As[16][68];     // [k][row], padded: conflict-free + 16B-aligned rows
    __shared__ float Bs[16][128];    // [k][col]
    int tid = threadIdx.x;
    int tx = tid & 15;               // col group: cols tx*8 .. +8
    int ty = tid >> 4;               // row group: rows ty*4 .. +4
    int row0 = blockIdx.x * 64;
    float acc[4][8] = {};

    for (int k0 = 0; k0 < 128; k0 += 16) {
        {   // A tile: 64x16, each thread one float4
            int r = tid >> 2;
            int cq = (tid & 3) << 2;
            int grow = row0 + r;
            float4 v = make_float4(0.f, 0.f, 0.f, 0.f);
            if (grow < M) v = *(const float4*)&A[grow * 128 + k0 + cq];
            As[cq + 0][r] = v.x;
            As[cq + 1][r] = v.y;
            As[cq + 2][r] = v.z;
            As[cq + 3][r] = v.w;
        }
        {   // B tile: 16x128, each thread two float4
            int br = tid >> 4;
            int bc = (tid & 15) << 3;
            float4 u0 = *(const float4*)&B[(k0 + br) * 128 + bc];
            float4 u1 = *(const float4*)&B[(k0 + br) * 128 + bc + 4];
            *(float4*)&Bs[br][bc] = u0;
            *(float4*)&Bs[br][bc + 4] = u1;
        }
        __syncthreads();
#pragma unroll
        for (int kk = 0; kk < 16; ++kk) {
            float a[4], b[8];
#pragma unroll
            for (int i = 0; i < 4; ++i) a[i] = As[kk][ty * 4 + i];
#pragma unroll
            for (int j = 0; j < 8; ++j) b[j] = Bs[kk][tx * 8 + j];
#pragma unroll
            for (int i = 0; i < 4; ++i)
#pragma unroll
                for (int j = 0; j < 8; ++j) acc[i][j] += a[i] * b[j];
        }
        __syncthreads();
    }

#pragma unroll
    for (int i = 0; i < 4; ++i) {
        int grow = row0 + ty * 4 + i;
        if (grow >= M) continue;
        float4* cp = (float4*)&C[grow * 128 + tx * 8];
        float4 c0 = cp[0], c1 = cp[1];
        float v[8] = {c0.x + acc[i][0], c0.y + acc[i][1], c0.z + acc[i][2], c0.w + acc[i][3],
                      c1.x + acc[i][4], c1.y + acc[i][5], c1.z + acc[i][6], c1.w + acc[i][7]};
        if (RELU) {
#pragma unroll
            for (int j = 0; j < 8; ++j) v[j] = fmaxf(v[j], 0.f) * 0.25f;
        }
        cp[0] = make_float4(v[0], v[1], v[2], v[3]);
        cp[1] = make_float4(v[4], v[5], v[6], v[7]);
    }
}

// ---------------- final linear: out[M,16] = h[M,128] @ W[128,16] + b ----------------

__global__ void final_linear_kernel(const float* __restrict__ h, const float* __restrict__ W,
                                    const float* __restrict__ bias, float* __restrict__ out) {
    __shared__ float Ws[128 * 16];
    __shared__ float Hs[16 * 132];   // 16 rows, stride 132 (bank-spread)
    int tid = threadIdx.x;
    int node0 = blockIdx.x * 16;
    for (int i = tid; i < 2048; i += 256) {
        Ws[i] = W[i];
        int gi = node0 * 128 + i;
        int r = i >> 7, c = i & 127;
        Hs[r * 132 + c] = (gi < NN * 128) ? h[gi] : 0.f;
    }
    __syncthreads();
    int g = tid >> 4;                // node within block
    int c = tid & 15;                // class
    int node = node0 + g;
    if (node >= NN) return;
    float acc = bias[c];
#pragma unroll 8
    for (int k = 0; k < 128; ++k) acc += Hs[g * 132 + k] * Ws[k * 16 + c];
    out[node * NCLS + c] = acc;
}

// ---------------- launch ----------------

extern "C" void kernel_launch(void* const* d_in, const int* in_sizes, int n_in,
                              void* d_out, int out_size, void* d_ws, size_t ws_size,
                              hipStream_t stream) {
    const float* x     = (const float*)d_in[0];
    const int*   e0    = (const int*)d_in[1];
    const int*   e1    = (const int*)d_in[2];
    const int*   e2    = (const int*)d_in[3];
    const int*   e3    = (const int*)d_in[4];
    const float* W_nbr = (const float*)d_in[5];
    const float* b_nbr = (const float*)d_in[6];
    const float* W_root= (const float*)d_in[7];
    const float* lin_w = (const float*)d_in[8];
    const float* lin_b = (const float*)d_in[9];
    float* out = (float*)d_out;

    // workspace bump allocator (256B aligned)
    char* p = (char*)d_ws;
    auto alloc = [&](size_t bytes) -> void* {
        void* q = (void*)p;
        p += (bytes + 255) & ~(size_t)255;
        return q;
    };
    int*   counts = (int*)alloc((size_t)RELS * NN * 4);
    int*   rowptr = (int*)alloc((size_t)RELS * (NN + 1) * 4);
    int*   col    = (int*)alloc((size_t)RELS * NE * 4);
    int*   bsums  = (int*)alloc((size_t)RELS * 128 * 4);
    float* Wsum   = (float*)alloc((size_t)2 * 16384 * 4);
    float* bsum   = (float*)alloc((size_t)2 * 128 * 4);
    float* agg    = (float*)alloc((size_t)NN * HID * 4);
    float* h0     = (float*)alloc((size_t)NN * HID * 4);
    float* h1     = (float*)alloc((size_t)NN * HID * 4);

    const int eblocks = (NE + 255) / 256;

    // CSR build (shared by both layers)
    hipMemsetAsync(counts, 0, (size_t)RELS * NN * 4, stream);
    hist_kernel<<<dim3(eblocks, RELS), 256, 0, stream>>>(e0, e1, e2, e3, counts);
    scanA_kernel<<<dim3(NCHUNK, RELS), SCAN_B, 0, stream>>>(counts, bsums);
    scanB_kernel<<<1, 64, 0, stream>>>(bsums, rowptr);
    scanC_kernel<<<dim3(NCHUNK, RELS), SCAN_B, 0, stream>>>(counts, bsums, rowptr);
    hipMemsetAsync(counts, 0, (size_t)RELS * NN * 4, stream);
    fill_kernel<<<dim3(eblocks, RELS), 256, 0, stream>>>(e0, e1, e2, e3, rowptr, counts, col);

    // weight pre-reduction
    wsum_kernel<<<128, 256, 0, stream>>>(W_root, b_nbr, Wsum, bsum);

    const int gemm_blocks = (NN + 63) / 64;

    for (int l = 0; l < 2; ++l) {
        const float* hin = (l == 0) ? x : h0;
        float* hout = (l == 0) ? h0 : h1;
        init_bias_kernel<<<(NN * HID + 255) / 256, 256, 0, stream>>>(hout, bsum + l * 128);
        for (int r = 0; r < RELS; ++r) {
            aggregate_kernel<<<NN / 2, 256, 0, stream>>>(rowptr + r * (NN + 1), col + r * NE,
                                                         hin, agg);
            gemm_acc_kernel<false><<<gemm_blocks, 256, 0, stream>>>(
                agg, W_nbr + ((size_t)l * RELS + r) * 16384, hout, NN);
        }
        gemm_acc_kernel<true><<<gemm_blocks, 256, 0, stream>>>(hin, Wsum + l * 16384, hout, NN);
    }

    final_linear_kernel<<<(NN + 15) / 16, 256, 0, stream>>>(h1, lin_w, lin_b, out);
}

// Round 2
// 1048.659 us; speedup vs baseline: 1.5261x; 1.5261x over previous
//
#include <hip/hip_runtime.h>
#include <hip/hip_bf16.h>

// Problem constants (match reference)
#define NN 100000
#define NE 500000
#define DD 128
#define HID 128
#define RELS 4
#define NCLS 16
#define SCAN_B 1024
#define NCHUNK ((NN + SCAN_B - 1) / SCAN_B)   // 98

__device__ __forceinline__ float bf2f(unsigned short u) {
    return __uint_as_float(((unsigned int)u) << 16);
}

// ---------------- CSR build ----------------

__global__ void hist_kernel(const int* __restrict__ e0, const int* __restrict__ e1,
                            const int* __restrict__ e2, const int* __restrict__ e3,
                            int* __restrict__ counts) {
    int i = blockIdx.x * 256 + threadIdx.x;
    int rel = blockIdx.y;
    if (i >= NE) return;
    const int* ep = (rel == 0) ? e0 : (rel == 1) ? e1 : (rel == 2) ? e2 : e3;
    int d = ep[NE + i];              // dst row
    atomicAdd(&counts[rel * NN + d], 1);
}

__global__ void scanA_kernel(const int* __restrict__ counts, int* __restrict__ bsums) {
    int rel = blockIdx.y, chunk = blockIdx.x;
    int i = chunk * SCAN_B + threadIdx.x;
    __shared__ int s[SCAN_B];
    int v = (i < NN) ? counts[rel * NN + i] : 0;
    s[threadIdx.x] = v;
    __syncthreads();
    for (int off = SCAN_B / 2; off > 0; off >>= 1) {
        if (threadIdx.x < off) s[threadIdx.x] += s[threadIdx.x + off];
        __syncthreads();
    }
    if (threadIdx.x == 0) bsums[rel * 128 + chunk] = s[0];
}

__global__ void scanB_kernel(int* __restrict__ bsums, int* __restrict__ rowptr) {
    int r = threadIdx.x;
    if (r < RELS) {
        int acc = 0;
        for (int c = 0; c < NCHUNK; ++c) {
            int v = bsums[r * 128 + c];
            bsums[r * 128 + c] = acc;
            acc += v;
        }
        rowptr[r * (NN + 1) + NN] = acc;   // == NE
    }
}

__global__ void scanC_kernel(const int* __restrict__ counts, const int* __restrict__ bsums,
                             int* __restrict__ rowptr) {
    int rel = blockIdx.y, chunk = blockIdx.x;
    int i = chunk * SCAN_B + threadIdx.x;
    __shared__ int s[SCAN_B];
    int v = (i < NN) ? counts[rel * NN + i] : 0;
    s[threadIdx.x] = v;
    __syncthreads();
    // Hillis-Steele inclusive scan
    for (int off = 1; off < SCAN_B; off <<= 1) {
        int add = (threadIdx.x >= (unsigned)off) ? s[threadIdx.x - off] : 0;
        __syncthreads();
        s[threadIdx.x] += add;
        __syncthreads();
    }
    if (i < NN)
        rowptr[rel * (NN + 1) + i] = bsums[rel * 128 + chunk] + s[threadIdx.x] - v;
}

__global__ void fill_kernel(const int* __restrict__ e0, const int* __restrict__ e1,
                            const int* __restrict__ e2, const int* __restrict__ e3,
                            const int* __restrict__ rowptr, int* __restrict__ cursor,
                            int* __restrict__ col) {
    int i = blockIdx.x * 256 + threadIdx.x;
    int rel = blockIdx.y;
    if (i >= NE) return;
    const int* ep = (rel == 0) ? e0 : (rel == 1) ? e1 : (rel == 2) ? e2 : e3;
    int src = ep[i];
    int dst = ep[NE + i];
    int p = atomicAdd(&cursor[rel * NN + dst], 1);
    col[rel * NE + rowptr[rel * (NN + 1) + dst] + p] = src;
}

// ---------------- weight pre-reduction ----------------
// Wsum[l] = sum_r W_root[l,r];  bsum[l] = sum_r b_nbr[l,r]

__global__ void wsum_kernel(const float* __restrict__ Wr, const float* __restrict__ bn,
                            float* __restrict__ Ws, float* __restrict__ bs) {
    int i = blockIdx.x * 256 + threadIdx.x;
    if (i < 2 * 16384) {
        int l = i >> 14, off = i & 16383;
        float a = 0.f;
        for (int r = 0; r < RELS; ++r) a += Wr[(l * RELS + r) * 16384 + off];
        Ws[i] = a;
    }
    if (i < 2 * 128) {
        int l = i >> 7, off = i & 127;
        float a = 0.f;
        for (int r = 0; r < RELS; ++r) a += bn[(l * RELS + r) * 128 + off];
        bs[i] = a;
    }
}

// ---------------- mean aggregation via CSR → bf16 concat buffer ----------------
// 64 lanes per node (float2 each), 4 nodes per 256-thread block, grid.y = relation.
// Unroll-by-4: 4 independent index loads + 4 independent row gathers in flight.

__global__ void aggregate_kernel(const int* __restrict__ rowptr, const int* __restrict__ col,
                                 const float* __restrict__ xin,
                                 __hip_bfloat16* __restrict__ cat) {
    int rel = blockIdx.y;
    int node = blockIdx.x * 4 + (threadIdx.x >> 6);
    int lane = threadIdx.x & 63;
    const int* __restrict__ rp = rowptr + rel * (NN + 1);
    const int* __restrict__ cl = col + (size_t)rel * NE;
    int s = rp[node], e = rp[node + 1];
    float a0x = 0.f, a0y = 0.f, a1x = 0.f, a1y = 0.f;
    float a2x = 0.f, a2y = 0.f, a3x = 0.f, a3y = 0.f;
    int k = s;
    for (; k + 4 <= e; k += 4) {
        int i0 = cl[k], i1 = cl[k + 1], i2 = cl[k + 2], i3 = cl[k + 3];
        float2 v0 = ((const float2*)(xin + (size_t)i0 * DD))[lane];
        float2 v1 = ((const float2*)(xin + (size_t)i1 * DD))[lane];
        float2 v2 = ((const float2*)(xin + (size_t)i2 * DD))[lane];
        float2 v3 = ((const float2*)(xin + (size_t)i3 * DD))[lane];
        a0x += v0.x; a0y += v0.y;
        a1x += v1.x; a1y += v1.y;
        a2x += v2.x; a2y += v2.y;
        a3x += v3.x; a3y += v3.y;
    }
    for (; k < e; ++k) {
        int i = cl[k];
        float2 v = ((const float2*)(xin + (size_t)i * DD))[lane];
        a0x += v.x; a0y += v.y;
    }
    float sc = (e > s) ? 1.0f / (float)(e - s) : 0.0f;
    float tx = (a0x + a1x + a2x + a3x) * sc;
    float ty = (a0y + a1y + a2y + a3y) * sc;
    __hip_bfloat162 o;
    o.x = __float2bfloat16(tx);
    o.y = __float2bfloat16(ty);
    *((__hip_bfloat162*)(cat + (size_t)node * 512 + rel * 128 + lane * 2)) = o;
}

// ---------------- fused layer GEMM ----------------
// hout = relu( 0.25 * (cat[M,512]@Wn[512,128] + hin[M,128]@Wr[128,128] + bsum) )
// BM=128, BN=128, BK=8, 256 threads, 8x8 per-thread tile, fp32 accumulate.
// In-place safe for hin==hout: each block reads only its own 128 rows.

__global__ __launch_bounds__(256, 2) void layer_gemm_kernel(
    const __hip_bfloat16* __restrict__ cat, const float* __restrict__ hin,
    const float* __restrict__ Wn, const float* __restrict__ Wr,
    const float* __restrict__ bsum, float* __restrict__ hout, int M) {
    __shared__ float As[8][132];     // [k][row], padded (132 = 16B-aligned rows)
    __shared__ float Bs[8][128];     // [k][col]
    int tid = threadIdx.x;
    int tx = tid & 15;               // col group: cols tx*8 .. +8
    int ty = tid >> 4;               // row group: rows ty*8 .. +8
    int row0 = blockIdx.x * 128;
    int lr = tid >> 1;               // A-load row 0..127
    int lc = (tid & 1) * 4;          // A-load col offset {0,4}
    int br = tid >> 5;               // B-load row 0..7
    int bc = (tid & 31) * 4;         // B-load col
    float acc[8][8] = {};

    // ---- phase 0: K=512 over bf16 cat, B = Wn ----
    for (int k0 = 0; k0 < 512; k0 += 8) {
        int grow = row0 + lr;
        ushort4 av = make_ushort4(0, 0, 0, 0);
        if (grow < M) av = *(const ushort4*)(cat + (size_t)grow * 512 + k0 + lc);
        As[lc + 0][lr] = bf2f(av.x);
        As[lc + 1][lr] = bf2f(av.y);
        As[lc + 2][lr] = bf2f(av.z);
        As[lc + 3][lr] = bf2f(av.w);
        *(float4*)&Bs[br][bc] = *(const float4*)&Wn[(k0 + br) * 128 + bc];
        __syncthreads();
#pragma unroll
        for (int kk = 0; kk < 8; ++kk) {
            float a[8], b[8];
            *(float4*)&a[0] = *(const float4*)&As[kk][ty * 8];
            *(float4*)&a[4] = *(const float4*)&As[kk][ty * 8 + 4];
            *(float4*)&b[0] = *(const float4*)&Bs[kk][tx * 8];
            *(float4*)&b[4] = *(const float4*)&Bs[kk][tx * 8 + 4];
#pragma unroll
            for (int i = 0; i < 8; ++i)
#pragma unroll
                for (int j = 0; j < 8; ++j) acc[i][j] += a[i] * b[j];
        }
        __syncthreads();
    }

    // ---- phase 1: K=128 over fp32 hin, B = Wr ----
    for (int k0 = 0; k0 < 128; k0 += 8) {
        int grow = row0 + lr;
        float4 av = make_float4(0.f, 0.f, 0.f, 0.f);
        if (grow < M) av = *(const float4*)(hin + (size_t)grow * 128 + k0 + lc);
        As[lc + 0][lr] = av.x;
        As[lc + 1][lr] = av.y;
        As[lc + 2][lr] = av.z;
        As[lc + 3][lr] = av.w;
        *(float4*)&Bs[br][bc] = *(const float4*)&Wr[(k0 + br) * 128 + bc];
        __syncthreads();
#pragma unroll
        for (int kk = 0; kk < 8; ++kk) {
            float a[8], b[8];
            *(float4*)&a[0] = *(const float4*)&As[kk][ty * 8];
            *(float4*)&a[4] = *(const float4*)&As[kk][ty * 8 + 4];
            *(float4*)&b[0] = *(const float4*)&Bs[kk][tx * 8];
            *(float4*)&b[4] = *(const float4*)&Bs[kk][tx * 8 + 4];
#pragma unroll
            for (int i = 0; i < 8; ++i)
#pragma unroll
                for (int j = 0; j < 8; ++j) acc[i][j] += a[i] * b[j];
        }
        __syncthreads();
    }

    // ---- epilogue: bias + ReLU*0.25, store ----
    float bias[8];
#pragma unroll
    for (int j = 0; j < 8; ++j) bias[j] = bsum[tx * 8 + j];
#pragma unroll
    for (int i = 0; i < 8; ++i) {
        int grow = row0 + ty * 8 + i;
        if (grow >= M) continue;
        float v[8];
#pragma unroll
        for (int j = 0; j < 8; ++j) v[j] = fmaxf((acc[i][j] + bias[j]) * 0.25f, 0.f);
        float4* cp = (float4*)(hout + (size_t)grow * 128 + tx * 8);
        cp[0] = make_float4(v[0], v[1], v[2], v[3]);
        cp[1] = make_float4(v[4], v[5], v[6], v[7]);
    }
}

// ---------------- final linear: out[M,16] = h[M,128] @ W[128,16] + b ----------------

__global__ void final_linear_kernel(const float* __restrict__ h, const float* __restrict__ W,
                                    const float* __restrict__ bias, float* __restrict__ out) {
    __shared__ float Ws[128 * 16];
    __shared__ float Hs[16 * 132];   // 16 rows, stride 132 (bank-spread)
    int tid = threadIdx.x;
    int node0 = blockIdx.x * 16;
    for (int i = tid; i < 2048; i += 256) {
        Ws[i] = W[i];
        int gi = node0 * 128 + i;
        int r = i >> 7, c = i & 127;
        Hs[r * 132 + c] = (gi < NN * 128) ? h[gi] : 0.f;
    }
    __syncthreads();
    int g = tid >> 4;                // node within block
    int c = tid & 15;                // class
    int node = node0 + g;
    if (node >= NN) return;
    float acc = bias[c];
#pragma unroll 8
    for (int k = 0; k < 128; ++k) acc += Hs[g * 132 + k] * Ws[k * 16 + c];
    out[node * NCLS + c] = acc;
}

// ---------------- launch ----------------

extern "C" void kernel_launch(void* const* d_in, const int* in_sizes, int n_in,
                              void* d_out, int out_size, void* d_ws, size_t ws_size,
                              hipStream_t stream) {
    const float* x     = (const float*)d_in[0];
    const int*   e0    = (const int*)d_in[1];
    const int*   e1    = (const int*)d_in[2];
    const int*   e2    = (const int*)d_in[3];
    const int*   e3    = (const int*)d_in[4];
    const float* W_nbr = (const float*)d_in[5];
    const float* b_nbr = (const float*)d_in[6];
    const float* W_root= (const float*)d_in[7];
    const float* lin_w = (const float*)d_in[8];
    const float* lin_b = (const float*)d_in[9];
    float* out = (float*)d_out;

    // workspace bump allocator (256B aligned)
    char* p = (char*)d_ws;
    auto alloc = [&](size_t bytes) -> void* {
        void* q = (void*)p;
        p += (bytes + 255) & ~(size_t)255;
        return q;
    };
    int*   counts = (int*)alloc((size_t)RELS * NN * 4);
    int*   rowptr = (int*)alloc((size_t)RELS * (NN + 1) * 4);
    int*   col    = (int*)alloc((size_t)RELS * NE * 4);
    int*   bsums  = (int*)alloc((size_t)RELS * 128 * 4);
    float* Wsum   = (float*)alloc((size_t)2 * 16384 * 4);
    float* bsum   = (float*)alloc((size_t)2 * 128 * 4);
    __hip_bfloat16* cat = (__hip_bfloat16*)alloc((size_t)NN * 512 * 2);
    float* h0     = (float*)alloc((size_t)NN * HID * 4);

    const int eblocks = (NE + 255) / 256;

    // CSR build (shared by both layers)
    hipMemsetAsync(counts, 0, (size_t)RELS * NN * 4, stream);
    hist_kernel<<<dim3(eblocks, RELS), 256, 0, stream>>>(e0, e1, e2, e3, counts);
    scanA_kernel<<<dim3(NCHUNK, RELS), SCAN_B, 0, stream>>>(counts, bsums);
    scanB_kernel<<<1, 64, 0, stream>>>(bsums, rowptr);
    scanC_kernel<<<dim3(NCHUNK, RELS), SCAN_B, 0, stream>>>(counts, bsums, rowptr);
    hipMemsetAsync(counts, 0, (size_t)RELS * NN * 4, stream);
    fill_kernel<<<dim3(eblocks, RELS), 256, 0, stream>>>(e0, e1, e2, e3, rowptr, counts, col);

    // weight pre-reduction
    wsum_kernel<<<128, 256, 0, stream>>>(W_root, b_nbr, Wsum, bsum);

    const int gemm_blocks = (NN + 127) / 128;

    // layer 1: x -> h0
    aggregate_kernel<<<dim3(NN / 4, RELS), 256, 0, stream>>>(rowptr, col, x, cat);
    layer_gemm_kernel<<<gemm_blocks, 256, 0, stream>>>(cat, x, W_nbr, Wsum, bsum, h0, NN);

    // layer 2: h0 -> h0 (in-place safe: block-local rows)
    aggregate_kernel<<<dim3(NN / 4, RELS), 256, 0, stream>>>(rowptr, col, h0, cat);
    layer_gemm_kernel<<<gemm_blocks, 256, 0, stream>>>(cat, h0, W_nbr + (size_t)RELS * 16384,
                                                       Wsum + 16384, bsum + 128, h0, NN);

    final_linear_kernel<<<(NN + 15) / 16, 256, 0, stream>>>(h0, lin_w, lin_b, out);
}

// Round 3
// 619.325 us; speedup vs baseline: 2.5840x; 1.6932x over previous
//
#include <hip/hip_runtime.h>
#include <hip/hip_bf16.h>

// Problem constants (match reference)
#define NN 100000
#define NE 500000
#define DD 128
#define HID 128
#define RELS 4
#define NCLS 16
#define KCAT 512
#define KTOT 640
#define SCAN_B 1024
#define NCHUNK ((NN + SCAN_B - 1) / SCAN_B)   // 98

typedef __attribute__((ext_vector_type(8))) short s16x8;
typedef __attribute__((ext_vector_type(4))) float f32x4;

__device__ __forceinline__ float bf2f(unsigned short u) {
    return __uint_as_float(((unsigned int)u) << 16);
}
__device__ __forceinline__ unsigned short f2bfbits(float f) {
    __hip_bfloat16 h = __float2bfloat16(f);
    return *reinterpret_cast<unsigned short*>(&h);
}

// ---------------- CSR build ----------------

__global__ void hist_kernel(const int* __restrict__ e0, const int* __restrict__ e1,
                            const int* __restrict__ e2, const int* __restrict__ e3,
                            int* __restrict__ counts) {
    int i = blockIdx.x * 256 + threadIdx.x;
    int rel = blockIdx.y;
    if (i >= NE) return;
    const int* ep = (rel == 0) ? e0 : (rel == 1) ? e1 : (rel == 2) ? e2 : e3;
    int d = ep[NE + i];              // dst row
    atomicAdd(&counts[rel * NN + d], 1);
}

__global__ void scanA_kernel(const int* __restrict__ counts, int* __restrict__ bsums) {
    int rel = blockIdx.y, chunk = blockIdx.x;
    int i = chunk * SCAN_B + threadIdx.x;
    __shared__ int s[SCAN_B];
    int v = (i < NN) ? counts[rel * NN + i] : 0;
    s[threadIdx.x] = v;
    __syncthreads();
    for (int off = SCAN_B / 2; off > 0; off >>= 1) {
        if (threadIdx.x < off) s[threadIdx.x] += s[threadIdx.x + off];
        __syncthreads();
    }
    if (threadIdx.x == 0) bsums[rel * 128 + chunk] = s[0];
}

__global__ void scanB_kernel(int* __restrict__ bsums, int* __restrict__ rowptr) {
    int r = threadIdx.x;
    if (r < RELS) {
        int acc = 0;
        for (int c = 0; c < NCHUNK; ++c) {
            int v = bsums[r * 128 + c];
            bsums[r * 128 + c] = acc;
            acc += v;
        }
        rowptr[r * (NN + 1) + NN] = acc;   // == NE
    }
}

__global__ void scanC_kernel(const int* __restrict__ counts, const int* __restrict__ bsums,
                             int* __restrict__ rowptr) {
    int rel = blockIdx.y, chunk = blockIdx.x;
    int i = chunk * SCAN_B + threadIdx.x;
    __shared__ int s[SCAN_B];
    int v = (i < NN) ? counts[rel * NN + i] : 0;
    s[threadIdx.x] = v;
    __syncthreads();
    for (int off = 1; off < SCAN_B; off <<= 1) {
        int add = (threadIdx.x >= (unsigned)off) ? s[threadIdx.x - off] : 0;
        __syncthreads();
        s[threadIdx.x] += add;
        __syncthreads();
    }
    if (i < NN)
        rowptr[rel * (NN + 1) + i] = bsums[rel * 128 + chunk] + s[threadIdx.x] - v;
}

__global__ void fill_kernel(const int* __restrict__ e0, const int* __restrict__ e1,
                            const int* __restrict__ e2, const int* __restrict__ e3,
                            const int* __restrict__ rowptr, int* __restrict__ cursor,
                            int* __restrict__ col) {
    int i = blockIdx.x * 256 + threadIdx.x;
    int rel = blockIdx.y;
    if (i >= NE) return;
    const int* ep = (rel == 0) ? e0 : (rel == 1) ? e1 : (rel == 2) ? e2 : e3;
    int src = ep[i];
    int dst = ep[NE + i];
    int p = atomicAdd(&cursor[rel * NN + dst], 1);
    col[rel * NE + rowptr[rel * (NN + 1) + dst] + p] = src;
}

// ---------------- weight conversion ----------------
// BT[l][n][k] (bf16, k-major rows): k<512 -> W_nbr[l][k>>7][k&127][n]
//                                   k>=512 -> sum_r W_root[l][r][k-512][n]
// bsum[l][c] = sum_r b_nbr[l][r][c]  (fp32)

__global__ void wconv_kernel(const float* __restrict__ Wn, const float* __restrict__ Wr,
                             const float* __restrict__ bn, __hip_bfloat16* __restrict__ BT,
                             float* __restrict__ bsum) {
    int idx = blockIdx.x * 256 + threadIdx.x;
    if (idx < 2 * 128 * KTOT) {
        int l = (idx >= 128 * KTOT) ? 1 : 0;
        int rem = idx - l * 128 * KTOT;
        int n = rem & 127;
        int k = rem >> 7;            // 0..639
        float v;
        if (k < KCAT) {
            v = Wn[(((size_t)l * RELS + (k >> 7)) * 128 + (k & 127)) * 128 + n];
        } else {
            int kk = k - KCAT;
            v = 0.f;
            for (int r = 0; r < RELS; ++r)
                v += Wr[(((size_t)l * RELS + r) * 128 + kk) * 128 + n];
        }
        BT[((size_t)l * 128 + n) * KTOT + k] = __float2bfloat16(v);
    } else if (idx < 2 * 128 * KTOT + 256) {
        int i = idx - 2 * 128 * KTOT;
        int l = i >> 7, c = i & 127;
        float a = 0.f;
        for (int r = 0; r < RELS; ++r) a += bn[((size_t)l * RELS + r) * 128 + c];
        bsum[i] = a;
    }
}

// ---------------- x -> bf16 into Abuf self columns ----------------

__global__ void x2bf_kernel(const float* __restrict__ x, __hip_bfloat16* __restrict__ Abuf) {
    int idx8 = blockIdx.x * 256 + threadIdx.x;    // one thread = 8 elements
    int node = idx8 >> 4;
    int c = (idx8 & 15) * 8;
    if (node >= NN) return;
    float4 f0 = *(const float4*)(x + (size_t)node * 128 + c);
    float4 f1 = *(const float4*)(x + (size_t)node * 128 + c + 4);
    uint4 o;
    o.x = f2bfbits(f0.x) | ((unsigned)f2bfbits(f0.y) << 16);
    o.y = f2bfbits(f0.z) | ((unsigned)f2bfbits(f0.w) << 16);
    o.z = f2bfbits(f1.x) | ((unsigned)f2bfbits(f1.y) << 16);
    o.w = f2bfbits(f1.z) | ((unsigned)f2bfbits(f1.w) << 16);
    *(uint4*)(Abuf + (size_t)node * KTOT + KCAT + c) = o;
}

// ---------------- mean aggregation: gather bf16 self-rows -> bf16 cat cols ----------------
// 16 lanes per node (16B each), 16 nodes per 256-thread block, grid.y = relation.
// 4 nodes per wave -> 4 independent gather chains; unroll-2 -> up to 8 loads in flight.

__global__ void aggregate_kernel(const int* __restrict__ rowptr, const int* __restrict__ col,
                                 __hip_bfloat16* __restrict__ Abuf) {
    int rel = blockIdx.y;
    int t = threadIdx.x;
    int node = blockIdx.x * 16 + (t >> 4);
    int lane = t & 15;
    const int* __restrict__ rp = rowptr + rel * (NN + 1);
    const int* __restrict__ cl = col + (size_t)rel * NE;
    int s = rp[node], e = rp[node + 1];
    float a[8] = {};
    int k = s;
    for (; k + 2 <= e; k += 2) {
        int i0 = cl[k], i1 = cl[k + 1];
        uint4 v0 = *(const uint4*)(Abuf + (size_t)i0 * KTOT + KCAT + lane * 8);
        uint4 v1 = *(const uint4*)(Abuf + (size_t)i1 * KTOT + KCAT + lane * 8);
        a[0] += bf2f(v0.x & 0xffff); a[1] += bf2f(v0.x >> 16);
        a[2] += bf2f(v0.y & 0xffff); a[3] += bf2f(v0.y >> 16);
        a[4] += bf2f(v0.z & 0xffff); a[5] += bf2f(v0.z >> 16);
        a[6] += bf2f(v0.w & 0xffff); a[7] += bf2f(v0.w >> 16);
        a[0] += bf2f(v1.x & 0xffff); a[1] += bf2f(v1.x >> 16);
        a[2] += bf2f(v1.y & 0xffff); a[3] += bf2f(v1.y >> 16);
        a[4] += bf2f(v1.z & 0xffff); a[5] += bf2f(v1.z >> 16);
        a[6] += bf2f(v1.w & 0xffff); a[7] += bf2f(v1.w >> 16);
    }
    if (k < e) {
        int i0 = cl[k];
        uint4 v0 = *(const uint4*)(Abuf + (size_t)i0 * KTOT + KCAT + lane * 8);
        a[0] += bf2f(v0.x & 0xffff); a[1] += bf2f(v0.x >> 16);
        a[2] += bf2f(v0.y & 0xffff); a[3] += bf2f(v0.y >> 16);
        a[4] += bf2f(v0.z & 0xffff); a[5] += bf2f(v0.z >> 16);
        a[6] += bf2f(v0.w & 0xffff); a[7] += bf2f(v0.w >> 16);
    }
    float sc = (e > s) ? 1.0f / (float)(e - s) : 0.0f;
    uint4 o;
    o.x = f2bfbits(a[0] * sc) | ((unsigned)f2bfbits(a[1] * sc) << 16);
    o.y = f2bfbits(a[2] * sc) | ((unsigned)f2bfbits(a[3] * sc) << 16);
    o.z = f2bfbits(a[4] * sc) | ((unsigned)f2bfbits(a[5] * sc) << 16);
    o.w = f2bfbits(a[6] * sc) | ((unsigned)f2bfbits(a[7] * sc) << 16);
    *(uint4*)(Abuf + (size_t)node * KTOT + rel * 128 + lane * 8) = o;
}

// ---------------- fused layer GEMM (bf16 MFMA) ----------------
// h = relu(0.25*(Abuf[M,640] @ BT^T + bsum)), written as bf16 into Abuf[:,512:640].
// BM=128, BN=128, BK=64, 256 threads = 4 waves (2x2), each wave 64x64 via 4x4
// mfma_f32_16x16x32_bf16 fragments. XOR-swizzled LDS (T2): byte ^= (row&7)<<4.
// In-place safe: each block reads only its own 128 A-rows, writes them in epilogue.

__global__ __launch_bounds__(256) void layer_gemm_kernel(
    __hip_bfloat16* __restrict__ Abuf, const __hip_bfloat16* __restrict__ BT,
    const float* __restrict__ bsum, int M) {
    __shared__ uint4 As4[1024];      // 16 KB: [128 rows][64 k] bf16, swizzled
    __shared__ uint4 Bs4[1024];      // 16 KB: [128 n  ][64 k] bf16, swizzled
    char* AsB = (char*)As4;
    char* BsB = (char*)Bs4;
    int t = threadIdx.x;
    int l = t & 63;
    int wave = t >> 6;
    int wm = wave >> 1, wn = wave & 1;
    int row0 = blockIdx.x * 128;

    int sr = t & 127;                // staging row (A row / B n)
    int sh = t >> 7;                 // which 32-k half
    const __hip_bfloat16* ga = Abuf + (size_t)(row0 + sr) * KTOT + sh * 32;
    const __hip_bfloat16* gb = BT + (size_t)sr * KTOT + sh * 32;
    bool arow_ok = (row0 + sr) < M;

    f32x4 acc[4][4];
#pragma unroll
    for (int i = 0; i < 4; ++i)
#pragma unroll
        for (int j = 0; j < 4; ++j) acc[i][j] = (f32x4){0.f, 0.f, 0.f, 0.f};

    int lrow = l & 15;               // fragment row/col within 16
    int lkg = l >> 4;                // k-group 0..3

    for (int k0 = 0; k0 < KTOT; k0 += 64) {
        uint4 av[4], bv[4];
#pragma unroll
        for (int j = 0; j < 4; ++j) {
            av[j] = arow_ok ? *(const uint4*)(ga + k0 + j * 8) : make_uint4(0, 0, 0, 0);
            bv[j] = *(const uint4*)(gb + k0 + j * 8);
        }
        if (k0 > 0) __syncthreads();   // previous iteration's reads done
#pragma unroll
        for (int j = 0; j < 4; ++j) {
            int q = sh * 4 + j;
            int off = sr * 128 + ((q ^ (sr & 7)) << 4);
            *(uint4*)(AsB + off) = av[j];
            *(uint4*)(BsB + off) = bv[j];
        }
        __syncthreads();
#pragma unroll
        for (int kk = 0; kk < 2; ++kk) {
            s16x8 af[4], bf[4];
            int q = kk * 4 + lkg;
#pragma unroll
            for (int mi = 0; mi < 4; ++mi) {
                int row = wm * 64 + mi * 16 + lrow;
                af[mi] = *(const s16x8*)(AsB + row * 128 + ((q ^ (row & 7)) << 4));
            }
#pragma unroll
            for (int ni = 0; ni < 4; ++ni) {
                int nrow = wn * 64 + ni * 16 + lrow;
                bf[ni] = *(const s16x8*)(BsB + nrow * 128 + ((q ^ (nrow & 7)) << 4));
            }
#pragma unroll
            for (int mi = 0; mi < 4; ++mi)
#pragma unroll
                for (int ni = 0; ni < 4; ++ni)
                    acc[mi][ni] = __builtin_amdgcn_mfma_f32_16x16x32_bf16(
                        af[mi], bf[ni], acc[mi][ni], 0, 0, 0);
        }
    }
    __syncthreads();   // all LDS reads done before epilogue writes global (Abuf rows)

    // epilogue: bias + relu*0.25 -> bf16 into Abuf[:,512+col]
    int cr = l >> 4;                 // row sub-group
    int cc = l & 15;                 // col within 16
#pragma unroll
    for (int ni = 0; ni < 4; ++ni) {
        int colg = wn * 64 + ni * 16 + cc;
        float bv2 = bsum[colg];
#pragma unroll
        for (int mi = 0; mi < 4; ++mi) {
#pragma unroll
            for (int r = 0; r < 4; ++r) {
                int grow = row0 + wm * 64 + mi * 16 + cr * 4 + r;
                if (grow < M) {
                    float v = fmaxf((acc[mi][ni][r] + bv2) * 0.25f, 0.f);
                    Abuf[(size_t)grow * KTOT + KCAT + colg] = __float2bfloat16(v);
                }
            }
        }
    }
}

// ---------------- final linear: out[M,16] = h[M,128] @ W[128,16] + b ----------------
// h read as bf16 from Abuf self columns (row stride 640).

__global__ void final_linear_kernel(const __hip_bfloat16* __restrict__ Abuf,
                                    const float* __restrict__ W,
                                    const float* __restrict__ bias, float* __restrict__ out) {
    __shared__ float Ws[128 * 16];
    __shared__ float Hs[16 * 132];
    int tid = threadIdx.x;
    int node0 = blockIdx.x * 16;
    for (int i = tid; i < 2048; i += 256) Ws[i] = W[i];
    {
        int g = tid >> 4, c = tid & 15;
        int node = node0 + g;
        float f[8] = {};
        if (node < NN) {
            uint4 v = *(const uint4*)(Abuf + (size_t)node * KTOT + KCAT + c * 8);
            f[0] = bf2f(v.x & 0xffff); f[1] = bf2f(v.x >> 16);
            f[2] = bf2f(v.y & 0xffff); f[3] = bf2f(v.y >> 16);
            f[4] = bf2f(v.z & 0xffff); f[5] = bf2f(v.z >> 16);
            f[6] = bf2f(v.w & 0xffff); f[7] = bf2f(v.w >> 16);
        }
#pragma unroll
        for (int j = 0; j < 8; ++j) Hs[g * 132 + c * 8 + j] = f[j];
    }
    __syncthreads();
    int g = tid >> 4;
    int c = tid & 15;
    int node = node0 + g;
    if (node >= NN) return;
    float acc = bias[c];
#pragma unroll 8
    for (int k = 0; k < 128; ++k) acc += Hs[g * 132 + k] * Ws[k * 16 + c];
    out[node * NCLS + c] = acc;
}

// ---------------- launch ----------------

extern "C" void kernel_launch(void* const* d_in, const int* in_sizes, int n_in,
                              void* d_out, int out_size, void* d_ws, size_t ws_size,
                              hipStream_t stream) {
    const float* x     = (const float*)d_in[0];
    const int*   e0    = (const int*)d_in[1];
    const int*   e1    = (const int*)d_in[2];
    const int*   e2    = (const int*)d_in[3];
    const int*   e3    = (const int*)d_in[4];
    const float* W_nbr = (const float*)d_in[5];
    const float* b_nbr = (const float*)d_in[6];
    const float* W_root= (const float*)d_in[7];
    const float* lin_w = (const float*)d_in[8];
    const float* lin_b = (const float*)d_in[9];
    float* out = (float*)d_out;

    // workspace bump allocator (256B aligned)
    char* p = (char*)d_ws;
    auto alloc = [&](size_t bytes) -> void* {
        void* q = (void*)p;
        p += (bytes + 255) & ~(size_t)255;
        return q;
    };
    int*   counts = (int*)alloc((size_t)RELS * NN * 4);
    int*   rowptr = (int*)alloc((size_t)RELS * (NN + 1) * 4);
    int*   col    = (int*)alloc((size_t)RELS * NE * 4);
    int*   bsums  = (int*)alloc((size_t)RELS * 128 * 4);
    float* bsum   = (float*)alloc((size_t)2 * 128 * 4);
    __hip_bfloat16* BT   = (__hip_bfloat16*)alloc((size_t)2 * 128 * KTOT * 2);
    __hip_bfloat16* Abuf = (__hip_bfloat16*)alloc((size_t)NN * KTOT * 2);

    const int eblocks = (NE + 255) / 256;

    // CSR build (shared by both layers)
    hipMemsetAsync(counts, 0, (size_t)RELS * NN * 4, stream);
    hist_kernel<<<dim3(eblocks, RELS), 256, 0, stream>>>(e0, e1, e2, e3, counts);
    scanA_kernel<<<dim3(NCHUNK, RELS), SCAN_B, 0, stream>>>(counts, bsums);
    scanB_kernel<<<1, 64, 0, stream>>>(bsums, rowptr);
    scanC_kernel<<<dim3(NCHUNK, RELS), SCAN_B, 0, stream>>>(counts, bsums, rowptr);
    hipMemsetAsync(counts, 0, (size_t)RELS * NN * 4, stream);
    fill_kernel<<<dim3(eblocks, RELS), 256, 0, stream>>>(e0, e1, e2, e3, rowptr, counts, col);

    // weights -> bf16 transposed (+ root-sum fold + bias sum)
    wconv_kernel<<<(2 * 128 * KTOT + 256 + 255) / 256, 256, 0, stream>>>(
        W_nbr, W_root, b_nbr, BT, bsum);

    // x -> bf16 self columns
    x2bf_kernel<<<(NN * 128 / 8 + 255) / 256, 256, 0, stream>>>(x, Abuf);

    const int gemm_blocks = (NN + 127) / 128;

    // layer 1
    aggregate_kernel<<<dim3(NN / 16, RELS), 256, 0, stream>>>(rowptr, col, Abuf);
    layer_gemm_kernel<<<gemm_blocks, 256, 0, stream>>>(Abuf, BT, bsum, NN);
    // layer 2
    aggregate_kernel<<<dim3(NN / 16, RELS), 256, 0, stream>>>(rowptr, col, Abuf);
    layer_gemm_kernel<<<gemm_blocks, 256, 0, stream>>>(Abuf, BT + (size_t)128 * KTOT,
                                                       bsum + 128, NN);

    final_linear_kernel<<<(NN + 15) / 16, 256, 0, stream>>>(Abuf, lin_w, lin_b, out);
}

// Round 4
// 595.878 us; speedup vs baseline: 2.6856x; 1.0393x over previous
//
#include <hip/hip_runtime.h>
#include <hip/hip_bf16.h>

// Problem constants (match reference)
#define NN 100000
#define NE 500000
#define DD 128
#define HID 128
#define RELS 4
#define NCLS 16
#define KCAT 512
#define KTOT 640
#define SCAN_B 1024
#define NCHUNK ((NN + SCAN_B - 1) / SCAN_B)   // 98

typedef __attribute__((ext_vector_type(8))) short s16x8;
typedef __attribute__((ext_vector_type(4))) float f32x4;

__device__ __forceinline__ float bf2f(unsigned short u) {
    return __uint_as_float(((unsigned int)u) << 16);
}
__device__ __forceinline__ unsigned short f2bfbits(float f) {
    __hip_bfloat16 h = __float2bfloat16(f);
    return *reinterpret_cast<unsigned short*>(&h);
}

// ---------------- CSR build ----------------

__global__ void hist_kernel(const int* __restrict__ e0, const int* __restrict__ e1,
                            const int* __restrict__ e2, const int* __restrict__ e3,
                            int* __restrict__ counts) {
    int i = blockIdx.x * 256 + threadIdx.x;
    int rel = blockIdx.y;
    if (i >= NE) return;
    const int* ep = (rel == 0) ? e0 : (rel == 1) ? e1 : (rel == 2) ? e2 : e3;
    int d = ep[NE + i];              // dst row
    atomicAdd(&counts[rel * NN + d], 1);
}

__global__ void scanA_kernel(const int* __restrict__ counts, int* __restrict__ bsums) {
    int rel = blockIdx.y, chunk = blockIdx.x;
    int i = chunk * SCAN_B + threadIdx.x;
    __shared__ int s[SCAN_B];
    int v = (i < NN) ? counts[rel * NN + i] : 0;
    s[threadIdx.x] = v;
    __syncthreads();
    for (int off = SCAN_B / 2; off > 0; off >>= 1) {
        if (threadIdx.x < off) s[threadIdx.x] += s[threadIdx.x + off];
        __syncthreads();
    }
    if (threadIdx.x == 0) bsums[rel * 128 + chunk] = s[0];
}

__global__ void scanB_kernel(int* __restrict__ bsums, int* __restrict__ rowptr) {
    int r = threadIdx.x;
    if (r < RELS) {
        int acc = 0;
        for (int c = 0; c < NCHUNK; ++c) {
            int v = bsums[r * 128 + c];
            bsums[r * 128 + c] = acc;
            acc += v;
        }
        rowptr[r * (NN + 1) + NN] = acc;   // == NE
    }
}

__global__ void scanC_kernel(const int* __restrict__ counts, const int* __restrict__ bsums,
                             int* __restrict__ rowptr) {
    int rel = blockIdx.y, chunk = blockIdx.x;
    int i = chunk * SCAN_B + threadIdx.x;
    __shared__ int s[SCAN_B];
    int v = (i < NN) ? counts[rel * NN + i] : 0;
    s[threadIdx.x] = v;
    __syncthreads();
    for (int off = 1; off < SCAN_B; off <<= 1) {
        int add = (threadIdx.x >= (unsigned)off) ? s[threadIdx.x - off] : 0;
        __syncthreads();
        s[threadIdx.x] += add;
        __syncthreads();
    }
    if (i < NN)
        rowptr[rel * (NN + 1) + i] = bsums[rel * 128 + chunk] + s[threadIdx.x] - v;
}

__global__ void fill_kernel(const int* __restrict__ e0, const int* __restrict__ e1,
                            const int* __restrict__ e2, const int* __restrict__ e3,
                            const int* __restrict__ rowptr, int* __restrict__ cursor,
                            int* __restrict__ col) {
    int i = blockIdx.x * 256 + threadIdx.x;
    int rel = blockIdx.y;
    if (i >= NE) return;
    const int* ep = (rel == 0) ? e0 : (rel == 1) ? e1 : (rel == 2) ? e2 : e3;
    int src = ep[i];
    int dst = ep[NE + i];
    int p = atomicAdd(&cursor[rel * NN + dst], 1);
    col[rel * NE + rowptr[rel * (NN + 1) + dst] + p] = src;
}

// ---------------- weight conversion ----------------
// BT[l][n][k] (bf16, k-major rows): k<512 -> W_nbr[l][k>>7][k&127][n]
//                                   k>=512 -> sum_r W_root[l][r][k-512][n]
// bsum[l][c] = sum_r b_nbr[l][r][c]  (fp32)

__global__ void wconv_kernel(const float* __restrict__ Wn, const float* __restrict__ Wr,
                             const float* __restrict__ bn, __hip_bfloat16* __restrict__ BT,
                             float* __restrict__ bsum) {
    int idx = blockIdx.x * 256 + threadIdx.x;
    if (idx < 2 * 128 * KTOT) {
        int l = (idx >= 128 * KTOT) ? 1 : 0;
        int rem = idx - l * 128 * KTOT;
        int n = rem & 127;
        int k = rem >> 7;            // 0..639
        float v;
        if (k < KCAT) {
            v = Wn[(((size_t)l * RELS + (k >> 7)) * 128 + (k & 127)) * 128 + n];
        } else {
            int kk = k - KCAT;
            v = 0.f;
            for (int r = 0; r < RELS; ++r)
                v += Wr[(((size_t)l * RELS + r) * 128 + kk) * 128 + n];
        }
        BT[((size_t)l * 128 + n) * KTOT + k] = __float2bfloat16(v);
    } else if (idx < 2 * 128 * KTOT + 256) {
        int i = idx - 2 * 128 * KTOT;
        int l = i >> 7, c = i & 127;
        float a = 0.f;
        for (int r = 0; r < RELS; ++r) a += bn[((size_t)l * RELS + r) * 128 + c];
        bsum[i] = a;
    }
}

// ---------------- x -> bf16 into Abuf self columns ----------------

__global__ void x2bf_kernel(const float* __restrict__ x, __hip_bfloat16* __restrict__ Abuf) {
    int idx8 = blockIdx.x * 256 + threadIdx.x;    // one thread = 8 elements
    int node = idx8 >> 4;
    int c = (idx8 & 15) * 8;
    if (node >= NN) return;
    float4 f0 = *(const float4*)(x + (size_t)node * 128 + c);
    float4 f1 = *(const float4*)(x + (size_t)node * 128 + c + 4);
    uint4 o;
    o.x = f2bfbits(f0.x) | ((unsigned)f2bfbits(f0.y) << 16);
    o.y = f2bfbits(f0.z) | ((unsigned)f2bfbits(f0.w) << 16);
    o.z = f2bfbits(f1.x) | ((unsigned)f2bfbits(f1.y) << 16);
    o.w = f2bfbits(f1.z) | ((unsigned)f2bfbits(f1.w) << 16);
    *(uint4*)(Abuf + (size_t)node * KTOT + KCAT + c) = o;
}

// ---------------- mean aggregation: gather bf16 self-rows -> bf16 cat cols ----------------
// 16 lanes per node (16B each), 16 nodes per 256-thread block, grid.y = relation.
// Unroll-4: 4 rows in flight per node, 16 per wave.

__global__ void aggregate_kernel(const int* __restrict__ rowptr, const int* __restrict__ col,
                                 __hip_bfloat16* __restrict__ Abuf) {
    int rel = blockIdx.y;
    int t = threadIdx.x;
    int node = blockIdx.x * 16 + (t >> 4);
    int lane = t & 15;
    const int* __restrict__ rp = rowptr + rel * (NN + 1);
    const int* __restrict__ cl = col + (size_t)rel * NE;
    int s = rp[node], e = rp[node + 1];
    float a[8] = {};
    int k = s;
    for (; k + 4 <= e; k += 4) {
        int i0 = cl[k], i1 = cl[k + 1], i2 = cl[k + 2], i3 = cl[k + 3];
        uint4 v0 = *(const uint4*)(Abuf + (size_t)i0 * KTOT + KCAT + lane * 8);
        uint4 v1 = *(const uint4*)(Abuf + (size_t)i1 * KTOT + KCAT + lane * 8);
        uint4 v2 = *(const uint4*)(Abuf + (size_t)i2 * KTOT + KCAT + lane * 8);
        uint4 v3 = *(const uint4*)(Abuf + (size_t)i3 * KTOT + KCAT + lane * 8);
        a[0] += bf2f(v0.x & 0xffff) + bf2f(v1.x & 0xffff) + bf2f(v2.x & 0xffff) + bf2f(v3.x & 0xffff);
        a[1] += bf2f(v0.x >> 16)    + bf2f(v1.x >> 16)    + bf2f(v2.x >> 16)    + bf2f(v3.x >> 16);
        a[2] += bf2f(v0.y & 0xffff) + bf2f(v1.y & 0xffff) + bf2f(v2.y & 0xffff) + bf2f(v3.y & 0xffff);
        a[3] += bf2f(v0.y >> 16)    + bf2f(v1.y >> 16)    + bf2f(v2.y >> 16)    + bf2f(v3.y >> 16);
        a[4] += bf2f(v0.z & 0xffff) + bf2f(v1.z & 0xffff) + bf2f(v2.z & 0xffff) + bf2f(v3.z & 0xffff);
        a[5] += bf2f(v0.z >> 16)    + bf2f(v1.z >> 16)    + bf2f(v2.z >> 16)    + bf2f(v3.z >> 16);
        a[6] += bf2f(v0.w & 0xffff) + bf2f(v1.w & 0xffff) + bf2f(v2.w & 0xffff) + bf2f(v3.w & 0xffff);
        a[7] += bf2f(v0.w >> 16)    + bf2f(v1.w >> 16)    + bf2f(v2.w >> 16)    + bf2f(v3.w >> 16);
    }
    for (; k < e; ++k) {
        int i0 = cl[k];
        uint4 v0 = *(const uint4*)(Abuf + (size_t)i0 * KTOT + KCAT + lane * 8);
        a[0] += bf2f(v0.x & 0xffff); a[1] += bf2f(v0.x >> 16);
        a[2] += bf2f(v0.y & 0xffff); a[3] += bf2f(v0.y >> 16);
        a[4] += bf2f(v0.z & 0xffff); a[5] += bf2f(v0.z >> 16);
        a[6] += bf2f(v0.w & 0xffff); a[7] += bf2f(v0.w >> 16);
    }
    float sc = (e > s) ? 1.0f / (float)(e - s) : 0.0f;
    uint4 o;
    o.x = f2bfbits(a[0] * sc) | ((unsigned)f2bfbits(a[1] * sc) << 16);
    o.y = f2bfbits(a[2] * sc) | ((unsigned)f2bfbits(a[3] * sc) << 16);
    o.z = f2bfbits(a[4] * sc) | ((unsigned)f2bfbits(a[5] * sc) << 16);
    o.w = f2bfbits(a[6] * sc) | ((unsigned)f2bfbits(a[7] * sc) << 16);
    *(uint4*)(Abuf + (size_t)node * KTOT + rel * 128 + lane * 8) = o;
}

// ---------------- fused layer GEMM (bf16 MFMA) ----------------
// h = relu(0.25*(Abuf[M,640] @ BT^T + bsum)), written as bf16 into Abuf[:,512:640].
// BM=128, BN=128, BK=64, 256 threads = 4 waves (2x2), each wave 64x64 via 4x4
// mfma_f32_16x16x32_bf16 fragments. XOR-swizzled LDS (T2).
// Epilogue stages the C tile in LDS (reusing A/B staging) and writes each row's
// 256B self-column region as contiguous uint4 stores (fixes write amplification).

__global__ __launch_bounds__(256) void layer_gemm_kernel(
    __hip_bfloat16* __restrict__ Abuf, const __hip_bfloat16* __restrict__ BT,
    const float* __restrict__ bsum, int M) {
    __shared__ uint4 smem4[2048];    // 32 KB: A(16K) + B(16K) staging; reused for C tile
    char* smem = (char*)smem4;
    char* AsB = smem;                // [128 rows][64 k] bf16, swizzled
    char* BsB = smem + 16384;        // [128 n  ][64 k] bf16, swizzled
    int t = threadIdx.x;
    int l = t & 63;
    int wave = t >> 6;
    int wm = wave >> 1, wn = wave & 1;
    int row0 = blockIdx.x * 128;

    int sr = t & 127;                // staging row (A row / B n)
    int sh = t >> 7;                 // which 32-k half
    const __hip_bfloat16* ga = Abuf + (size_t)(row0 + sr) * KTOT + sh * 32;
    const __hip_bfloat16* gb = BT + (size_t)sr * KTOT + sh * 32;
    bool arow_ok = (row0 + sr) < M;

    f32x4 acc[4][4];
#pragma unroll
    for (int i = 0; i < 4; ++i)
#pragma unroll
        for (int j = 0; j < 4; ++j) acc[i][j] = (f32x4){0.f, 0.f, 0.f, 0.f};

    int lrow = l & 15;               // fragment row/col within 16
    int lkg = l >> 4;                // k-group 0..3

    for (int k0 = 0; k0 < KTOT; k0 += 64) {
        uint4 av[4], bv[4];
#pragma unroll
        for (int j = 0; j < 4; ++j) {
            av[j] = arow_ok ? *(const uint4*)(ga + k0 + j * 8) : make_uint4(0, 0, 0, 0);
            bv[j] = *(const uint4*)(gb + k0 + j * 8);
        }
        if (k0 > 0) __syncthreads();   // previous iteration's LDS reads done
#pragma unroll
        for (int j = 0; j < 4; ++j) {
            int q = sh * 4 + j;
            int off = sr * 128 + ((q ^ (sr & 7)) << 4);
            *(uint4*)(AsB + off) = av[j];
            *(uint4*)(BsB + off) = bv[j];
        }
        __syncthreads();
#pragma unroll
        for (int kk = 0; kk < 2; ++kk) {
            s16x8 af[4], bf[4];
            int q = kk * 4 + lkg;
#pragma unroll
            for (int mi = 0; mi < 4; ++mi) {
                int row = wm * 64 + mi * 16 + lrow;
                af[mi] = *(const s16x8*)(AsB + row * 128 + ((q ^ (row & 7)) << 4));
            }
#pragma unroll
            for (int ni = 0; ni < 4; ++ni) {
                int nrow = wn * 64 + ni * 16 + lrow;
                bf[ni] = *(const s16x8*)(BsB + nrow * 128 + ((q ^ (nrow & 7)) << 4));
            }
#pragma unroll
            for (int mi = 0; mi < 4; ++mi)
#pragma unroll
                for (int ni = 0; ni < 4; ++ni)
                    acc[mi][ni] = __builtin_amdgcn_mfma_f32_16x16x32_bf16(
                        af[mi], bf[ni], acc[mi][ni], 0, 0, 0);
        }
    }
    __syncthreads();   // A/B staging dead from here; reuse smem for C tile

    // ---- stage C tile in LDS: bf16[128 rows][128 cols], 16B-chunk XOR swizzle ----
    {
        int cr = l >> 4;             // row sub-group 0..3
        int cc = l & 15;             // col within 16
#pragma unroll
        for (int ni = 0; ni < 4; ++ni) {
            int colg = wn * 64 + ni * 16 + cc;
            float bv2 = bsum[colg];
#pragma unroll
            for (int mi = 0; mi < 4; ++mi) {
#pragma unroll
                for (int r = 0; r < 4; ++r) {
                    int row = wm * 64 + mi * 16 + cr * 4 + r;
                    float v = fmaxf((acc[mi][ni][r] + bv2) * 0.25f, 0.f);
                    int byte = (row * 256 + colg * 2) ^ ((row & 7) << 4);
                    *(unsigned short*)(smem + byte) = f2bfbits(v);
                }
            }
        }
    }
    __syncthreads();

    // ---- contiguous row writes: thread t owns row t>>1, half t&1 (128B) ----
    {
        int row = t >> 1;
        int half = t & 1;
        int grow = row0 + row;
        if (grow < M) {
            __hip_bfloat16* dst = Abuf + (size_t)grow * KTOT + KCAT + half * 64;
#pragma unroll
            for (int j = 0; j < 8; ++j) {
                int byte = (row * 256 + half * 128 + j * 16) ^ ((row & 7) << 4);
                *(uint4*)(dst + j * 8) = *(const uint4*)(smem + byte);
            }
        }
    }
}

// ---------------- final linear: out[M,16] = h[M,128] @ W[128,16] + b ----------------

__global__ void final_linear_kernel(const __hip_bfloat16* __restrict__ Abuf,
                                    const float* __restrict__ W,
                                    const float* __restrict__ bias, float* __restrict__ out) {
    __shared__ float Ws[128 * 16];
    __shared__ float Hs[16 * 132];
    int tid = threadIdx.x;
    int node0 = blockIdx.x * 16;
    for (int i = tid; i < 2048; i += 256) Ws[i] = W[i];
    {
        int g = tid >> 4, c = tid & 15;
        int node = node0 + g;
        float f[8] = {};
        if (node < NN) {
            uint4 v = *(const uint4*)(Abuf + (size_t)node * KTOT + KCAT + c * 8);
            f[0] = bf2f(v.x & 0xffff); f[1] = bf2f(v.x >> 16);
            f[2] = bf2f(v.y & 0xffff); f[3] = bf2f(v.y >> 16);
            f[4] = bf2f(v.z & 0xffff); f[5] = bf2f(v.z >> 16);
            f[6] = bf2f(v.w & 0xffff); f[7] = bf2f(v.w >> 16);
        }
#pragma unroll
        for (int j = 0; j < 8; ++j) Hs[g * 132 + c * 8 + j] = f[j];
    }
    __syncthreads();
    int g = tid >> 4;
    int c = tid & 15;
    int node = node0 + g;
    if (node >= NN) return;
    float acc = bias[c];
#pragma unroll 8
    for (int k = 0; k < 128; ++k) acc += Hs[g * 132 + k] * Ws[k * 16 + c];
    out[node * NCLS + c] = acc;
}

// ---------------- launch ----------------

extern "C" void kernel_launch(void* const* d_in, const int* in_sizes, int n_in,
                              void* d_out, int out_size, void* d_ws, size_t ws_size,
                              hipStream_t stream) {
    const float* x     = (const float*)d_in[0];
    const int*   e0    = (const int*)d_in[1];
    const int*   e1    = (const int*)d_in[2];
    const int*   e2    = (const int*)d_in[3];
    const int*   e3    = (const int*)d_in[4];
    const float* W_nbr = (const float*)d_in[5];
    const float* b_nbr = (const float*)d_in[6];
    const float* W_root= (const float*)d_in[7];
    const float* lin_w = (const float*)d_in[8];
    const float* lin_b = (const float*)d_in[9];
    float* out = (float*)d_out;

    // workspace bump allocator (256B aligned)
    char* p = (char*)d_ws;
    auto alloc = [&](size_t bytes) -> void* {
        void* q = (void*)p;
        p += (bytes + 255) & ~(size_t)255;
        return q;
    };
    int*   counts = (int*)alloc((size_t)RELS * NN * 4);
    int*   rowptr = (int*)alloc((size_t)RELS * (NN + 1) * 4);
    int*   col    = (int*)alloc((size_t)RELS * NE * 4);
    int*   bsums  = (int*)alloc((size_t)RELS * 128 * 4);
    float* bsum   = (float*)alloc((size_t)2 * 128 * 4);
    __hip_bfloat16* BT   = (__hip_bfloat16*)alloc((size_t)2 * 128 * KTOT * 2);
    __hip_bfloat16* Abuf = (__hip_bfloat16*)alloc((size_t)NN * KTOT * 2);

    const int eblocks = (NE + 255) / 256;

    // CSR build (shared by both layers)
    hipMemsetAsync(counts, 0, (size_t)RELS * NN * 4, stream);
    hist_kernel<<<dim3(eblocks, RELS), 256, 0, stream>>>(e0, e1, e2, e3, counts);
    scanA_kernel<<<dim3(NCHUNK, RELS), SCAN_B, 0, stream>>>(counts, bsums);
    scanB_kernel<<<1, 64, 0, stream>>>(bsums, rowptr);
    scanC_kernel<<<dim3(NCHUNK, RELS), SCAN_B, 0, stream>>>(counts, bsums, rowptr);
    hipMemsetAsync(counts, 0, (size_t)RELS * NN * 4, stream);
    fill_kernel<<<dim3(eblocks, RELS), 256, 0, stream>>>(e0, e1, e2, e3, rowptr, counts, col);

    // weights -> bf16 transposed (+ root-sum fold + bias sum)
    wconv_kernel<<<(2 * 128 * KTOT + 256 + 255) / 256, 256, 0, stream>>>(
        W_nbr, W_root, b_nbr, BT, bsum);

    // x -> bf16 self columns
    x2bf_kernel<<<(NN * 128 / 8 + 255) / 256, 256, 0, stream>>>(x, Abuf);

    const int gemm_blocks = (NN + 127) / 128;

    // layer 1
    aggregate_kernel<<<dim3(NN / 16, RELS), 256, 0, stream>>>(rowptr, col, Abuf);
    layer_gemm_kernel<<<gemm_blocks, 256, 0, stream>>>(Abuf, BT, bsum, NN);
    // layer 2
    aggregate_kernel<<<dim3(NN / 16, RELS), 256, 0, stream>>>(rowptr, col, Abuf);
    layer_gemm_kernel<<<gemm_blocks, 256, 0, stream>>>(Abuf, BT + (size_t)128 * KTOT,
                                                       bsum + 128, NN);

    final_linear_kernel<<<(NN + 15) / 16, 256, 0, stream>>>(Abuf, lin_w, lin_b, out);
}